// Round 15
// baseline (649.707 us; speedup 1.0000x reference)
//
#include <hip/hip_runtime.h>
#include <hip/hip_bf16.h>
#include <math.h>

#define NN 768
#define FF 128
#define VV 64
#define RH 16
#define SPLITK 32
#define SEND_PER_KC 24          // 768 / SPLITK
#define NITER 3                 // SEND_PER_KC / 8 senders per iter
#define KSTEPS 384              // 12288 / 32
#define NT_S 8                  // scalar n-tiles (128/16)
#define NT_V 16                 // vector n-tiles (256/16)
#define MB_N 24                 // M-blocks (768/32)
#define GRID 768
#define PREP_TOT (KSTEPS * 24 * 64)   // 589824

typedef __attribute__((ext_vector_type(8))) short bf16x8_t;
typedef __attribute__((ext_vector_type(4))) float f32x4;

__device__ __forceinline__ float silu_f(float a) {
  return a * __builtin_amdgcn_rcpf(1.0f + __expf(-a));
}

__device__ __forceinline__ short f2bf(float f) {
  __hip_bfloat16 h = __float2bfloat16(f);  // RNE; pairs into v_cvt_pk_bf16_f32
  return __builtin_bit_cast(short, h);
}

__device__ __forceinline__ float bf2f(unsigned short v) {
  return __builtin_bit_cast(float, (unsigned)v << 16);
}

// grid barrier: slot zeroed per replay by captured hipMemsetAsync.
// arrive (device-scope add) + spin (agent-scope acquire load).
// __threadfence() = agent-scope fence (wb/inv L1+L2) -> cross-XCD visibility.
__device__ __forceinline__ void gbar(unsigned* slot) {
  __threadfence();
  __syncthreads();
  if (threadIdx.x == 0) {
    atomicAdd(slot, 1u);
    while (__hip_atomic_load(slot, __ATOMIC_ACQUIRE, __HIP_MEMORY_SCOPE_AGENT) < GRID)
      __builtin_amdgcn_s_sleep(2);
  }
  __syncthreads();
  __threadfence();
}

// ---------------------------------------------------------------------------
// MEGA kernel: [layer0] gbar [prep] gbar [edge GEMM] gbar [final].
// grid = 768 = 3 blocks/CU exactly; launch_bounds(256,3) + 38.9 KB LDS
// guarantee co-residency. All phase bodies are the R14-verified code.
// ---------------------------------------------------------------------------
__global__ __launch_bounds__(256, 3) void mega_kernel(
    const float* __restrict__ x,
    const float* __restrict__ embed,
    const float* __restrict__ Wr1,     // [2][16]
    const float* __restrict__ Wr2s,    // [2][16][128]
    const float* __restrict__ Wr2v,    // [2][16][64]
    const float* __restrict__ Wsv,     // [2][128][64]
    const float* __restrict__ Wss,     // [2][128][128]
    const float* __restrict__ Wvs,     // [2][64][128]
    const float* __restrict__ Wvv,     // [2][64][64]
    const float* __restrict__ Wro_s1,
    const float* __restrict__ Wro_s2,
    const float* __restrict__ Wro_v1,
    const float* __restrict__ Wro_v2,
    float* hs, float* hsv, float* hv,
    unsigned short* Ps, unsigned short* Pv,
    unsigned short* Bs, unsigned short* Bv,
    unsigned* bar,
    float* out)
{
  __shared__ float S[9728];   // 38.9 KB, aliased per phase
  const int tid = threadIdx.x;
  const int b   = blockIdx.x;

  //========================= PHASE 1: layer0 (R14 verbatim) ================
  {
    float* accT  = S;            // 256*33 = 8448
    float* red8  = S + 8448;     // 8*32 = 256
    float* fin   = S + 8704;     // 64
    float* cvs   = S + 8768;     // 64
    float* as_l  = S + 8832;     // 128
    float* av_l  = S + 8960;     // 192
    float* inv_l = S + 9152;     // 64
    float* hsn   = S + 9216;     // 128
    float* redn  = S + 9344;     // 256
    const int r = b;
    const float* Wsv1 = Wsv + FF * VV;

    if (tid < 64) {
      float a = 0.f;
      #pragma unroll 8
      for (int f = 0; f < FF; ++f) a += embed[f] * Wsv[f * VV + tid];
      cvs[tid] = a;
    }

    float wr1[RH];
    #pragma unroll
    for (int hh = 0; hh < RH; ++hh) wr1[hh] = Wr1[hh];

    const float xr0 = x[r * 3 + 0], xr1 = x[r * 3 + 1], xr2 = x[r * 3 + 2];

    float acc[64];
    #pragma unroll
    for (int i = 0; i < 64; ++i) acc[i] = 0.f;

    #pragma unroll
    for (int ss = 0; ss < 3; ++ss) {
      const int s = tid + ss * 256;
      const float vx = x[s * 3 + 0] - xr0;
      const float vy = x[s * 3 + 1] - xr1;
      const float vz = x[s * 3 + 2] - xr2;
      const float d  = __builtin_amdgcn_sqrtf(vx * vx + vy * vy + vz * vz);
      const float iv = __builtin_amdgcn_rcpf(d + 1e-8f);
      const float ux = vx * iv, uy = vy * iv, uz = vz * iv;
      #pragma unroll
      for (int h = 0; h < RH; ++h) {
        const float rf = silu_f(d * wr1[h]);
        acc[h * 4 + 0] += rf;
        acc[h * 4 + 1] += rf * ux;
        acc[h * 4 + 2] += rf * uy;
        acc[h * 4 + 3] += rf * uz;
      }
    }

    // transpose-reduce, two 33-pitch rounds
    #pragma unroll
    for (int i = 0; i < 32; ++i) accT[tid * 33 + i] = acc[i];
    __syncthreads();
    {
      const int j2 = tid & 31, q2 = tid >> 5;
      float a0 = 0.f, a1 = 0.f;
      #pragma unroll 8
      for (int rr = 0; rr < 32; rr += 2) {
        a0 += accT[(q2 * 32 + rr) * 33 + j2];
        a1 += accT[(q2 * 32 + rr + 1) * 33 + j2];
      }
      red8[q2 * 32 + j2] = a0 + a1;
    }
    __syncthreads();
    if (tid < 32) {
      float a = 0.f;
      #pragma unroll
      for (int g = 0; g < 8; ++g) a += red8[g * 32 + tid];
      fin[tid] = a;
    }
    __syncthreads();
    #pragma unroll
    for (int i = 0; i < 32; ++i) accT[tid * 33 + i] = acc[32 + i];
    __syncthreads();
    {
      const int j2 = tid & 31, q2 = tid >> 5;
      float a0 = 0.f, a1 = 0.f;
      #pragma unroll 8
      for (int rr = 0; rr < 32; rr += 2) {
        a0 += accT[(q2 * 32 + rr) * 33 + j2];
        a1 += accT[(q2 * 32 + rr + 1) * 33 + j2];
      }
      red8[q2 * 32 + j2] = a0 + a1;
    }
    __syncthreads();
    if (tid < 32) {
      float a = 0.f;
      #pragma unroll
      for (int g = 0; g < 8; ++g) a += red8[g * 32 + tid];
      fin[32 + tid] = a;
    }
    __syncthreads();

    if (tid < FF) {
      float a = 0.f;
      #pragma unroll
      for (int hh = 0; hh < RH; ++hh) a += fin[hh * 4] * Wr2s[hh * FF + tid];
      as_l[tid] = a * embed[tid] * (1.0f / 64.0f);
    }
    if (tid < 192) {
      const int v = tid / 3, d = tid - v * 3;
      float a = 0.f;
      #pragma unroll
      for (int hh = 0; hh < RH; ++hh) a += fin[hh * 4 + 1 + d] * Wr2v[hh * VV + v];
      av_l[tid] = a * cvs[v] * (1.0f / 64.0f);
    }
    __syncthreads();

    if (tid < VV) {
      const float a0 = av_l[tid * 3 + 0], a1 = av_l[tid * 3 + 1], a2 = av_l[tid * 3 + 2];
      inv_l[tid] = a0 * a0 + a1 * a1 + a2 * a2;
    }
    __syncthreads();

    {
      const int f = tid & 127, part = tid >> 7;
      float a = 0.f;
      const float* wp = Wss + (part * 64) * FF + f;
      #pragma unroll 8
      for (int kk = 0; kk < 64; ++kk) a += as_l[part * 64 + kk] * wp[kk * FF];
      const float* vp = Wvs + (part * 32) * FF + f;
      #pragma unroll 8
      for (int vv = 0; vv < 32; ++vv) a += inv_l[part * 32 + vv] * vp[vv * FF];
      redn[part * 128 + f] = a;
    }
    __syncthreads();

    if (tid < FF) {
      const float hnew = silu_f(embed[tid] + redn[tid] + redn[128 + tid]);
      hs[(size_t)r * FF + tid] = hnew;
      hsn[tid] = hnew;
    }
    if (tid < 192) {
      const int w = tid / 3, d = tid - w * 3;
      float a = 0.f;
      #pragma unroll 8
      for (int v = 0; v < VV; ++v) a += av_l[v * 3 + d] * Wvv[v * VV + w];
      hv[(size_t)r * 192 + tid] = a;
    }
    __syncthreads();

    {
      const int v = tid & 63, part = tid >> 6;
      float a = 0.f;
      const float* wp = Wsv1 + (part * 32) * VV + v;
      #pragma unroll 8
      for (int f = 0; f < 32; ++f) a += hsn[part * 32 + f] * wp[f * VV];
      redn[tid] = a;
    }
    __syncthreads();
    if (tid < VV)
      hsv[(size_t)r * VV + tid] = redn[tid] + redn[64 + tid] + redn[128 + tid] + redn[192 + tid];
  }
  gbar(bar + 0);

  //========================= PHASE 2: prep (grid-strided) ==================
  {
    const float* W2s = Wr2s + RH * FF;
    const float* W2v = Wr2v + RH * VV;
    for (int gid = b * 256 + tid; gid < PREP_TOT; gid += GRID * 256) {
      const int lane  = gid & 63;
      const int tmp   = gid >> 6;
      const int ntile = tmp % 24;
      const int kstep = tmp / 24;
      const int qq = lane >> 4;
      const int s  = kstep * 2 + (qq >> 1);
      const int hb = (qq & 1) * 8;

      bf16x8_t o;
      if (ntile < NT_S) {
        const int f = ntile * 16 + (lane & 15);
        const float hf = hs[s * FF + f] * 0.015625f;
        #pragma unroll
        for (int e = 0; e < 8; ++e)
          o[e] = f2bf(hf * W2s[(hb + e) * FF + f]);
        *(bf16x8_t*)&Bs[((size_t)(kstep * NT_S + ntile) * 64 + lane) * 8] = o;
      } else {
        const int nt2 = ntile - NT_S;
        const int n   = nt2 * 16 + (lane & 15);
        int v; float scale;
        if (n < 192) { const int dd = n >> 6; v = n & 63;
                       scale = x[s * 3 + dd] * hsv[s * VV + v] * 0.015625f; }
        else         { v = n - 192; scale = hsv[s * VV + v] * 0.015625f; }
        #pragma unroll
        for (int e = 0; e < 8; ++e)
          o[e] = f2bf(scale * W2v[(hb + e) * VV + v]);
        *(bf16x8_t*)&Bv[((size_t)(kstep * NT_V + nt2) * 64 + lane) * 8] = o;
      }
    }
  }
  gbar(bar + 1);

  //========================= PHASE 3: edge GEMM (SPLITK=32) ================
  {
    unsigned short* A_lds = (unsigned short*)S;            // 8 KB
    unsigned short* G_lds = (unsigned short*)(S + 2048);   // 8 KB

    // XCD swizzle: 768 = 8 * 96; xcd owns kc in [4*xcd, 4*xcd+4)
    const int wg = ((b & 7) * 96) + (b >> 3);
    const int kc = wg / MB_N;        // 0..31
    const int mb = wg - kc * MB_N;   // 0..23

    const int lane = tid & 63;
    const int w    = tid >> 6;
    const float* Wr1e = Wr1 + RH;

    float wr1[RH];
    #pragma unroll
    for (int h = 0; h < RH; ++h) wr1[h] = Wr1e[h];

    const int r_local = tid & 31;
    const int s_ii    = tid >> 5;
    const int r = mb * 32 + r_local;
    const int mt_w  = r_local >> 4;
    const int ks_w  = s_ii >> 1;
    const int lane0 = (r_local & 15) + ((s_ii & 1) << 5);

    const float xr0 = x[r * 3 + 0], xr1 = x[r * 3 + 1], xr2 = x[r * 3 + 2];
    float sx[NITER], sy[NITER], sz[NITER];
    #pragma unroll
    for (int it = 0; it < NITER; ++it) {
      const int s = kc * SEND_PER_KC + it * 8 + s_ii;
      sx[it] = x[s * 3 + 0]; sy[it] = x[s * 3 + 1]; sz[it] = x[s * 3 + 2];
    }

    f32x4 accS[4], accV[8];
    #pragma unroll
    for (int i = 0; i < 4; ++i) accS[i] = (f32x4){0.f, 0.f, 0.f, 0.f};
    #pragma unroll
    for (int i = 0; i < 8; ++i) accV[i] = (f32x4){0.f, 0.f, 0.f, 0.f};

    for (int it = 0; it < NITER; ++it) {
      {
        const float vx = sx[it] - xr0;
        const float vy = sy[it] - xr1;
        const float vz = sz[it] - xr2;
        const float dd = __builtin_amdgcn_sqrtf(vx * vx + vy * vy + vz * vz);
        const float iv = __builtin_amdgcn_rcpf(dd + 1e-8f);
        float sv[RH];
        #pragma unroll
        for (int h = 0; h < RH; ++h) sv[h] = silu_f(dd * wr1[h]);
        bf16x8_t o0, o1, g0, g1;
        #pragma unroll
        for (int h = 0; h < 8; ++h) {
          o0[h] = f2bf(sv[h]);
          o1[h] = f2bf(sv[h + 8]);
          g0[h] = f2bf(sv[h] * iv);
          g1[h] = f2bf(sv[h + 8] * iv);
        }
        const int off0 = ((ks_w * 2 + mt_w) * 64 + lane0) * 8;
        *(bf16x8_t*)&A_lds[off0]       = o0;
        *(bf16x8_t*)&A_lds[off0 + 128] = o1;
        *(bf16x8_t*)&G_lds[off0]       = g0;
        *(bf16x8_t*)&G_lds[off0 + 128] = g1;
      }
      __syncthreads();

      const int kgb = kc * (SEND_PER_KC / 2) + it * 4;
      #pragma unroll
      for (int ks = 0; ks < 4; ++ks) {
        const bf16x8_t b0 =
            *(const bf16x8_t*)&Bs[((size_t)((kgb + ks) * NT_S + 2 * w) * 64 + lane) * 8];
        const bf16x8_t b1 =
            *(const bf16x8_t*)&Bs[((size_t)((kgb + ks) * NT_S + 2 * w + 1) * 64 + lane) * 8];
        bf16x8_t bv[4];
        #pragma unroll
        for (int j = 0; j < 4; ++j)
          bv[j] = *(const bf16x8_t*)&Bv[((size_t)((kgb + ks) * NT_V + 4 * w + j) * 64 + lane) * 8];
        #pragma unroll
        for (int mt = 0; mt < 2; ++mt) {
          const int aoff = ((ks * 2 + mt) * 64 + lane) * 8;
          const bf16x8_t a  = *(const bf16x8_t*)&A_lds[aoff];
          const bf16x8_t ag = *(const bf16x8_t*)&G_lds[aoff];
          accS[mt * 2 + 0] = __builtin_amdgcn_mfma_f32_16x16x32_bf16(a, b0, accS[mt * 2 + 0], 0, 0, 0);
          accS[mt * 2 + 1] = __builtin_amdgcn_mfma_f32_16x16x32_bf16(a, b1, accS[mt * 2 + 1], 0, 0, 0);
          #pragma unroll
          for (int j = 0; j < 4; ++j)
            accV[mt * 4 + j] = __builtin_amdgcn_mfma_f32_16x16x32_bf16(ag, bv[j], accV[mt * 4 + j], 0, 0, 0);
        }
      }
      __syncthreads();
    }

    const int rowq = (lane >> 4) << 2;
    #pragma unroll
    for (int j = 0; j < 2; ++j) {
      const int col = (2 * w + j) * 16 + (lane & 15);
      #pragma unroll
      for (int mt = 0; mt < 2; ++mt) {
        #pragma unroll
        for (int reg = 0; reg < 4; ++reg) {
          const int row = mb * 32 + mt * 16 + rowq + reg;
          Ps[((size_t)kc * NN + row) * FF + col] =
              (unsigned short)f2bf(accS[mt * 2 + j][reg]);
        }
      }
    }
    #pragma unroll
    for (int j = 0; j < 4; ++j) {
      const int col = (4 * w + j) * 16 + (lane & 15);
      #pragma unroll
      for (int mt = 0; mt < 2; ++mt) {
        #pragma unroll
        for (int reg = 0; reg < 4; ++reg) {
          const int row = mb * 32 + mt * 16 + rowq + reg;
          Pv[((size_t)kc * NN + row) * 256 + col] =
              (unsigned short)f2bf(accV[mt * 4 + j][reg]);
        }
      }
    }
  }
  gbar(bar + 2);

  //========================= PHASE 4: final (256-thread) ===================
  {
    float* as_l  = S;            // 128
    float* pvs_l = S + 128;      // 256
    float* av_l  = S + 384;      // 192
    float* inv_l = S + 576;      // 64
    float* hsn   = S + 640;      // 128
    float* hv_l  = S + 768;      // 192
    float* red   = S + 960;      // 256
    float* t1    = S + 1216;     // 128
    float* tv1   = S + 1344;     // 192
    const int n = b;
    const float* Wss1 = Wss + FF * FF;
    const float* Wvs1 = Wvs + VV * FF;
    const float* Wvv1 = Wvv + VV * VV;

    // fused splitK reduce (bf16 loads)
    {
      float a = 0.f;
      #pragma unroll
      for (int kc = 0; kc < SPLITK; ++kc)
        a += bf2f(Pv[((size_t)kc * NN + n) * 256 + tid]);
      pvs_l[tid] = a;
      if (tid < FF) {
        float c = 0.f;
        #pragma unroll
        for (int kc = 0; kc < SPLITK; ++kc)
          c += bf2f(Ps[((size_t)kc * NN + n) * FF + tid]);
        as_l[tid] = c;
      }
    }
    __syncthreads();

    if (tid < VV) {
      const float base = pvs_l[192 + tid];
      const float a0 = pvs_l[tid]       - x[n * 3 + 0] * base;
      const float a1 = pvs_l[64 + tid]  - x[n * 3 + 1] * base;
      const float a2 = pvs_l[128 + tid] - x[n * 3 + 2] * base;
      av_l[tid * 3 + 0] = a0; av_l[tid * 3 + 1] = a1; av_l[tid * 3 + 2] = a2;
      inv_l[tid] = a0 * a0 + a1 * a1 + a2 * a2;
    }
    __syncthreads();

    // hs GEMV: 2-way K split
    {
      const int f = tid & 127, part = tid >> 7;
      float a = 0.f;
      const float* wp = Wss1 + (part * 64) * FF + f;
      #pragma unroll 8
      for (int kk = 0; kk < 64; ++kk) a += as_l[part * 64 + kk] * wp[kk * FF];
      const float* vp = Wvs1 + (part * 32) * FF + f;
      #pragma unroll 8
      for (int vv = 0; vv < 32; ++vv) a += inv_l[part * 32 + vv] * vp[vv * FF];
      red[part * 128 + f] = a;
    }
    __syncthreads();

    if (tid < FF)
      hsn[tid] = silu_f(hs[n * FF + tid] + red[tid] + red[128 + tid]);
    if (tid < 192) {
      const int w = tid / 3, d = tid - w * 3;
      float a = 0.f;
      #pragma unroll 8
      for (int v = 0; v < VV; ++v) a += av_l[v * 3 + d] * Wvv1[v * VV + w];
      hv_l[tid] = hv[n * 192 + tid] + a;
    }
    __syncthreads();

    // readout
    {
      const int f = tid & 127, part = tid >> 7;
      float a = 0.f;
      const float* wp = Wro_s1 + (part * 64) * FF + f;
      #pragma unroll 8
      for (int kk = 0; kk < 64; ++kk) a += hsn[part * 64 + kk] * wp[kk * FF];
      red[part * 128 + f] = a;
    }
    __syncthreads();
    if (tid < FF) t1[tid] = silu_f(red[tid] + red[128 + tid]);
    if (tid < 192) {
      const int w = tid / 3, d = tid - w * 3;
      float a = 0.f;
      #pragma unroll 8
      for (int v = 0; v < VV; ++v) a += hv_l[v * 3 + d] * Wro_v1[v * VV + w];
      tv1[tid] = a;
    }
    __syncthreads();

    if (tid < 128) {
      const int o = tid & 63, part = tid >> 6;
      float a = 0.f;
      const float* wp = Wro_s2 + (part * 64) * 64 + o;
      #pragma unroll 8
      for (int f = 0; f < 64; ++f) a += t1[part * 64 + f] * wp[f * 64];
      red[tid] = a;
    }
    if (tid >= 160) {
      const int j = tid - 160;          // 0..95
      const int w2 = j / 3, d = j - w2 * 3;
      float a = 0.f;
      #pragma unroll 8
      for (int wv = 0; wv < VV; ++wv) a += tv1[wv * 3 + d] * Wro_v2[wv * 32 + w2];
      out[n * 160 + 64 + j] = a;
    }
    __syncthreads();
    if (tid < 64) out[n * 160 + tid] = red[tid] + red[64 + tid];
  }
}

// ---------------------------------------------------------------------------
extern "C" void kernel_launch(void* const* d_in, const int* in_sizes, int n_in,
                              void* d_out, int out_size, void* d_ws, size_t ws_size,
                              hipStream_t stream) {
  const float* x      = (const float*)d_in[0];
  const float* embed  = (const float*)d_in[3];
  const float* Wr1    = (const float*)d_in[4];   // [2][1][16]
  const float* Wr2s   = (const float*)d_in[5];   // [2][16][128]
  const float* Wr2v   = (const float*)d_in[6];   // [2][16][64]
  const float* Wsv    = (const float*)d_in[7];   // [2][128][64]
  const float* Wss    = (const float*)d_in[8];   // [2][128][128]
  const float* Wvs    = (const float*)d_in[9];   // [2][64][128]
  const float* Wvv    = (const float*)d_in[10];  // [2][64][64]
  const float* Wro_s1 = (const float*)d_in[11];
  const float* Wro_s2 = (const float*)d_in[12];
  const float* Wro_v1 = (const float*)d_in[13];
  const float* Wro_v2 = (const float*)d_in[14];

  unsigned* bar = (unsigned*)d_ws;                       // 3 slots (pad 256 B)
  float* hs  = (float*)((char*)d_ws + 256);              // 768*128 f32
  float* hsv = hs + NN * FF;                             // 768*64  f32
  float* hv  = hsv + NN * VV;                            // 768*192 f32
  unsigned short* Ps = (unsigned short*)(hv + NN * 192); // 32*768*128 bf16
  unsigned short* Pv = Ps + (size_t)SPLITK * NN * FF;    // 32*768*256 bf16
  unsigned short* Bs = Pv + (size_t)SPLITK * NN * 256;   // 12288*128 bf16
  unsigned short* Bv = Bs + (size_t)12288 * 128;         // 12288*256 bf16
  float* out = (float*)d_out;

  hipMemsetAsync(bar, 0, 16, stream);   // zero barrier slots (capturable)

  mega_kernel<<<GRID, 256, 0, stream>>>(
      x, embed, Wr1, Wr2s, Wr2v, Wsv, Wss, Wvs, Wvv,
      Wro_s1, Wro_s2, Wro_v1, Wro_v2,
      hs, hsv, hv, Ps, Pv, Bs, Bv, bar, out);
}